// Round 4
// baseline (789.330 us; speedup 1.0000x reference)
//
#include <hip/hip_runtime.h>
#include <hip/hip_bf16.h>
#include <stdint.h>

// ---------------- problem constants ----------------
#define E_ 8
#define C_ 1024
#define H_ 2752
#define NTOK 8192            // B*T = 4*2048
#define CAP_ROWS 18432       // 16384 assignments + 8*256 pad, 256-aligned
#define ROUTED_MB 72         // CAP_ROWS/256
#define SHARED_MB 32         // NTOK/256
#define SHARED_HBASE 18432
#define HROWS 26624          // CAP_ROWS + NTOK

typedef unsigned short u16;
typedef __attribute__((ext_vector_type(8))) short bf16x8;   // 8 bf16 in 4 VGPRs
typedef __attribute__((ext_vector_type(4))) float f32x4;

// ---------------- ws layout (bytes) ----------------
static constexpr size_t SZ_XB    = (size_t)NTOK * C_ * 2;
static constexpr size_t SZ_WT    = (size_t)E_ * H_ * C_ * 2;
static constexpr size_t SZ_SWT   = (size_t)H_ * C_ * 2;
static constexpr size_t SZ_H     = (size_t)HROWS * H_ * 2;

static constexpr size_t OFF_XB   = 0;
static constexpr size_t OFF_W1T  = OFF_XB   + SZ_XB;
static constexpr size_t OFF_W3T  = OFF_W1T  + SZ_WT;
static constexpr size_t OFF_W2T  = OFF_W3T  + SZ_WT;
static constexpr size_t OFF_SW1T = OFF_W2T  + SZ_WT;
static constexpr size_t OFF_SW3T = OFF_SW1T + SZ_SWT;
static constexpr size_t OFF_SW2T = OFF_SW3T + SZ_SWT;
static constexpr size_t OFF_H    = OFF_SW2T + SZ_SWT;
static constexpr size_t OFF_ZP   = OFF_H    + SZ_H;                 // 16KB zero page
static constexpr size_t OFF_RIDX = OFF_ZP   + 16384;                // int[NTOK*2]
static constexpr size_t OFF_RW   = OFF_RIDX + (size_t)NTOK*2*4;     // float[NTOK*2]
static constexpr size_t OFF_OFFS = OFF_RW   + (size_t)NTOK*2*4;     // int[16]
static constexpr size_t OFF_PTOK = OFF_OFFS + 64;                   // int[CAP_ROWS]
static constexpr size_t OFF_PW   = OFF_PTOK + (size_t)CAP_ROWS*4;   // float[CAP_ROWS]
static constexpr size_t WS_NEED  = OFF_PW   + (size_t)CAP_ROWS*4;

// ---------------- helpers ----------------
__device__ __forceinline__ u16 f2bf(float f) {
  union { float f; uint32_t u; } v; v.f = f;
  uint32_t r = v.u + 0x7FFFu + ((v.u >> 16) & 1u);   // RNE
  return (u16)(r >> 16);
}

// async global->LDS, 16B per lane; LDS base wave-uniform, lane offset automatic.
__device__ __forceinline__ void gld16(const void* g, void* l) {
  uint32_t lo = (uint32_t)(uintptr_t)l;
  lo = __builtin_amdgcn_readfirstlane(lo);
  __builtin_amdgcn_global_load_lds(
      (const __attribute__((address_space(1))) void*)g,
      (__attribute__((address_space(3))) void*)(uintptr_t)lo, 16, 0, 0);
}

#define MFMA16(A,B,C) __builtin_amdgcn_mfma_f32_16x16x32_bf16((A),(B),(C),0,0,0)
#define BARX() do { asm volatile("" ::: "memory"); __builtin_amdgcn_s_barrier(); \
                    asm volatile("" ::: "memory"); } while (0)
#define VMC(N) asm volatile("s_waitcnt vmcnt(" #N ")" ::: "memory")

// ---------------- gating: fp32 scores, top-2, plus x->bf16 ----------------
__global__ __launch_bounds__(256) void gate_kernel(
    const float* __restrict__ x, const float* __restrict__ gw,
    const float* __restrict__ bias, u16* __restrict__ xb,
    int* __restrict__ ridx, float* __restrict__ rw)
{
  const int n = blockIdx.x, t = threadIdx.x;
  const float4 v = *(const float4*)(x + (size_t)n * C_ + t * 4);
  union { u16 u[4]; uint2 d; } pk;
  pk.u[0] = f2bf(v.x); pk.u[1] = f2bf(v.y); pk.u[2] = f2bf(v.z); pk.u[3] = f2bf(v.w);
  *(uint2*)(xb + (size_t)n * C_ + t * 4) = pk.d;

  float p[E_];
#pragma unroll
  for (int e = 0; e < E_; ++e) {
    const float4 g = *(const float4*)(gw + (size_t)e * C_ + t * 4);
    p[e] = v.x * g.x + v.y * g.y + v.z * g.z + v.w * g.w;
  }
#pragma unroll
  for (int e = 0; e < E_; ++e)
    for (int off = 32; off > 0; off >>= 1) p[e] += __shfl_down(p[e], off);

  __shared__ float red[4][E_];
  const int wv = t >> 6;
  if ((t & 63) == 0) {
#pragma unroll
    for (int e = 0; e < E_; ++e) red[wv][e] = p[e];
  }
  __syncthreads();
  if (t == 0) {
    float sc[E_], rt[E_];
#pragma unroll
    for (int e = 0; e < E_; ++e) {
      const float d = red[0][e] + red[1][e] + red[2][e] + red[3][e];
      const float s = 1.f / (1.f + expf(-d));
      sc[e] = s; rt[e] = s + bias[e];
    }
    int i0 = 0; float b0 = rt[0];
#pragma unroll
    for (int e = 1; e < E_; ++e) if (rt[e] > b0) { b0 = rt[e]; i0 = e; }
    int i1 = -1; float b1 = -1e30f;
#pragma unroll
    for (int e = 0; e < E_; ++e) if (e != i0 && rt[e] > b1) { b1 = rt[e]; i1 = e; }
    const float s0 = sc[i0], s1 = sc[i1];
    const float inv = 1.f / (s0 + s1 + 1e-8f);
    ridx[2 * n] = i0; ridx[2 * n + 1] = i1;
    rw[2 * n] = s0 * inv; rw[2 * n + 1] = s1 * inv;
  }
}

// ---------------- weight transpose + fp32->bf16 ----------------
__global__ __launch_bounds__(256) void transpose_cs_kernel(
    const float* __restrict__ w1, const float* __restrict__ w3,
    const float* __restrict__ sw1, const float* __restrict__ sw3,
    u16* __restrict__ w1t, u16* __restrict__ w3t,
    u16* __restrict__ sw1t, u16* __restrict__ sw3t)
{
  const int z = blockIdx.z;
  const float* src; u16* dst;
  if      (z < 8)  { src = w1 + (size_t)z * C_ * H_;       dst = w1t + (size_t)z * H_ * C_; }
  else if (z < 16) { src = w3 + (size_t)(z - 8) * C_ * H_; dst = w3t + (size_t)(z - 8) * H_ * C_; }
  else if (z == 16){ src = sw1; dst = sw1t; }
  else             { src = sw3; dst = sw3t; }
  __shared__ float tile[32][33];
  const int tx = threadIdx.x, ty = threadIdx.y;
  const int s0 = blockIdx.x * 32;   // H dim
  const int r0 = blockIdx.y * 32;   // C dim
#pragma unroll
  for (int i = 0; i < 4; ++i)
    tile[ty + 8 * i][tx] = src[(size_t)(r0 + ty + 8 * i) * H_ + s0 + tx];
  __syncthreads();
#pragma unroll
  for (int i = 0; i < 4; ++i)
    dst[(size_t)(s0 + ty + 8 * i) * C_ + r0 + tx] = f2bf(tile[tx][ty + 8 * i]);
}

__global__ __launch_bounds__(256) void transpose_sc_kernel(
    const float* __restrict__ w2, const float* __restrict__ sw2,
    u16* __restrict__ w2t, u16* __restrict__ sw2t)
{
  const int z = blockIdx.z;
  const float* src; u16* dst;
  if (z < 8) { src = w2 + (size_t)z * H_ * C_; dst = w2t + (size_t)z * C_ * H_; }
  else       { src = sw2; dst = sw2t; }
  __shared__ float tile[32][33];
  const int tx = threadIdx.x, ty = threadIdx.y;
  const int s0 = blockIdx.x * 32;   // C dim
  const int r0 = blockIdx.y * 32;   // H dim
#pragma unroll
  for (int i = 0; i < 4; ++i)
    tile[ty + 8 * i][tx] = src[(size_t)(r0 + ty + 8 * i) * C_ + s0 + tx];
  __syncthreads();
#pragma unroll
  for (int i = 0; i < 4; ++i)
    dst[(size_t)(s0 + ty + 8 * i) * H_ + r0 + tx] = f2bf(tile[tx][ty + 8 * i]);
}

// ---------------- deterministic routing scan/scatter (single block) ----------------
__global__ __launch_bounds__(256) void route_scan_kernel(
    const int* __restrict__ ridx, const float* __restrict__ rw,
    int* __restrict__ offsets, int* __restrict__ perm_tok, float* __restrict__ perm_w)
{
  __shared__ int cnt[256][E_];
  __shared__ int pref[E_][257];
  __shared__ int offs[E_ + 1];
  __shared__ int totals[E_];
  const int t = threadIdx.x;
#pragma unroll
  for (int e = 0; e < E_; ++e) cnt[t][e] = 0;
  for (int j = 0; j < 64; ++j) { const int e = ridx[t * 64 + j]; cnt[t][e]++; }
  __syncthreads();
  if (t < E_) {
    int run = 0;
    for (int i = 0; i < 256; ++i) { pref[t][i] = run; run += cnt[i][t]; }
    totals[t] = run; pref[t][256] = run;
  }
  __syncthreads();
  if (t == 0) {
    int o = 0;
    for (int e = 0; e < E_; ++e) { offs[e] = o; o += (totals[e] + 255) & ~255; }
    offs[E_] = o;
    for (int i = 0; i <= E_; ++i) offsets[i] = offs[i];
  }
  __syncthreads();
#pragma unroll
  for (int e = 0; e < E_; ++e) cnt[t][e] = offs[e] + pref[e][t];
  for (int j = 0; j < 64; ++j) {
    const int a = t * 64 + j;
    const int e = ridx[a];
    const int p = cnt[t][e]++;
    perm_tok[p] = a >> 1;
    perm_w[p] = rw[a];
  }
  __syncthreads();
  for (int e = 0; e < E_; ++e) {
    for (int p = offs[e] + totals[e] + t; p < offs[e + 1]; p += 256) {
      perm_tok[p] = 0; perm_w[p] = 0.f;     // pads: valid dummy row, zero weight
    }
  }
}

// =====================================================================
// GEMM1 (2 phases/tile x 32 MFMA): h = silu(x@W1) * (x@W3) -> bf16
// BM=256, BN=128, BK=64(128B rows), 8 waves (2Mx4N).
// LDS: A[2buf][256][128B]=64KB, B1[2buf][128][128B]=32KB, B3=32KB -> 128KB.
// Swizzle (r1-proven, 0 conflicts): LDS[r][c16] = global[r][c16 ^ (r&7)];
// read chunk for kslice kk: (kk*4+lhi) ^ (l15&7). 128B staging segments.
// Counted vmcnt: VMC(4) at ph0-end, VMC(2) at ph1-end, never 0 mid-loop.
// =====================================================================
__global__ __launch_bounds__(512, 2) void gemm1_2p(
    const u16* __restrict__ xb, const u16* __restrict__ w1t_all,
    const u16* __restrict__ w3t_all, const u16* __restrict__ sw1t,
    const u16* __restrict__ sw3t, u16* __restrict__ hbuf,
    const int* __restrict__ offsets, const int* __restrict__ ptok)
{
  __shared__ char lds[131072];
  const int t = threadIdx.x;
  const int bx = blockIdx.x;
  const int n0 = blockIdx.y * 128;

  const u16 *b1w, *b3w; int row0; size_t hr0; int gather;
  if (bx < ROUTED_MB) {
    row0 = bx * 256;
    if (row0 >= offsets[8]) return;
    int e = 0;
#pragma unroll
    for (int i = 0; i < 7; ++i) if (row0 >= offsets[i + 1]) e = i + 1;
    b1w = w1t_all + (size_t)e * (H_ * C_);
    b3w = w3t_all + (size_t)e * (H_ * C_);
    hr0 = (size_t)row0; gather = 1;
  } else {
    row0 = (bx - ROUTED_MB) * 256;
    b1w = sw1t; b3w = sw3t; hr0 = (size_t)SHARED_HBASE + row0; gather = 0;
  }

  // staging: call = 8KB = 64 rows x 128B. thread t -> row sr=t>>3, chunk t&7.
  // source chunk pre-swizzled by row parity (8-slot XOR).
  const int sr = t >> 3;
  const int scb = (((t & 7) ^ (sr & 7)) << 4);
  const char* aS[4]; const char* b1S[2]; const char* b3S[2];
#pragma unroll
  for (int c = 0; c < 4; ++c) {
    const int r = row0 + c * 64 + sr;
    const int tok = gather ? ptok[r] : r;
    aS[c] = (const char*)xb + (size_t)tok * 2048 + scb;
  }
#pragma unroll
  for (int c = 0; c < 2; ++c) {
    int nb = n0 + c * 64 + sr; if (nb > H_ - 1) nb = H_ - 1;   // N tail clamp
    b1S[c] = (const char*)b1w + (size_t)nb * 2048 + scb;
    b3S[c] = (const char*)b3w + (size_t)nb * 2048 + scb;
  }
  const int wb = (t >> 6) << 10;
  char* ldsp = (char*)lds;

#define SA1(kt,c) gld16(aS[c]  + (kt)*128, ldsp + ((kt)&1)*32768 + (c)*8192 + wb)
#define SB1(kt,c) gld16(b1S[c] + (kt)*128, ldsp + 65536 + ((kt)&1)*16384 + (c)*8192 + wb)
#define SB3(kt,c) gld16(b3S[c] + (kt)*128, ldsp + 98304 + ((kt)&1)*16384 + (c)*8192 + wb)

  const int lane = t & 63, l15 = lane & 15, lhi = lane >> 4;
  const int wv = t >> 6, wm = wv >> 2, wn = wv & 3;
  const int co0 = ((lhi ^ (l15 & 7)) << 4);        // kslice 0 chunk byte
  const int co1 = (((4 + lhi) ^ (l15 & 7)) << 4);  // kslice 1 chunk byte
  const int arow = wm * 16384 + l15 * 128;         // + mf*2048
  const int brow = wn * 4096 + l15 * 128;          // + nf*2048

  bf16x8 a[4][2], rb1[2][2], rb3[2][2];
  f32x4 acc1[8][2], acc3[8][2];
#pragma unroll
  for (int i = 0; i < 8; ++i)
#pragma unroll
    for (int j = 0; j < 2; ++j) { acc1[i][j] = f32x4{0,0,0,0}; acc3[i][j] = f32x4{0,0,0,0}; }

#define LB(p) do { _Pragma("unroll") for (int nf = 0; nf < 2; ++nf) { \
  rb1[nf][0] = *(const bf16x8*)(ldsp + 65536 + (p)*16384 + brow + nf*2048 + co0); \
  rb1[nf][1] = *(const bf16x8*)(ldsp + 65536 + (p)*16384 + brow + nf*2048 + co1); \
  rb3[nf][0] = *(const bf16x8*)(ldsp + 98304 + (p)*16384 + brow + nf*2048 + co0); \
  rb3[nf][1] = *(const bf16x8*)(ldsp + 98304 + (p)*16384 + brow + nf*2048 + co1); } } while (0)
#define LA(p,mh) do { _Pragma("unroll") for (int mf = 0; mf < 4; ++mf) { \
  a[mf][0] = *(const bf16x8*)(ldsp + (p)*32768 + arow + ((mh)*4+mf)*2048 + co0); \
  a[mf][1] = *(const bf16x8*)(ldsp + (p)*32768 + arow + ((mh)*4+mf)*2048 + co1); } } while (0)
#define MM(mh) do { __builtin_amdgcn_s_setprio(1); \
  _Pragma("unroll") for (int kh = 0; kh < 2; ++kh) \
    _Pragma("unroll") for (int mf = 0; mf < 4; ++mf) \
      _Pragma("unroll") for (int nf = 0; nf < 2; ++nf) { \
        acc1[(mh)*4+mf][nf] = MFMA16(a[mf][kh], rb1[nf][kh], acc1[(mh)*4+mf][nf]); \
        acc3[(mh)*4+mf][nf] = MFMA16(a[mf][kh], rb3[nf][kh], acc3[(mh)*4+mf][nf]); } \
  __builtin_amdgcn_s_setprio(0); } while (0)

  // prologue: tile 0, need-order A0,A2,B1_0,B1_1,B3_0,B3_1,A1,A3
  SA1(0,0); SA1(0,2); SB1(0,0); SB1(0,1); SB3(0,0); SB3(0,1); SA1(0,1); SA1(0,3);
  VMC(2); BARX();

#pragma unroll 1
  for (int j = 0; j < 16; ++j) {
    const int p = j & 1;
    const bool more = (j < 15);
    // ph0: mh0 (both kslices)
    LB(p); LA(p, 0);
    if (more) { SA1(j+1,0); SA1(j+1,2); SB1(j+1,0); SB1(j+1,1); }
    BARX(); MM(0);
    if (more) { VMC(4); } else { VMC(0); }
    BARX();
    // ph1: mh1
    LA(p, 1);
    if (more) { SB3(j+1,0); SB3(j+1,1); SA1(j+1,1); SA1(j+1,3); }
    BARX(); MM(1);
    if (more) { VMC(2); }
    BARX();
  }

  // epilogue: silu(acc1)*acc3 -> bf16 h.  C/D map: row=lhi*4+q, col=l15.
  const int rb_ = wm * 128 + lhi * 4;
  const int cb_ = n0 + wn * 32 + l15;
#pragma unroll
  for (int mf = 0; mf < 8; ++mf)
#pragma unroll
    for (int q = 0; q < 4; ++q) {
      const int r = rb_ + mf * 16 + q;
      u16* hrow = hbuf + (hr0 + r) * H_;
#pragma unroll
      for (int nf = 0; nf < 2; ++nf) {
        const int c = cb_ + nf * 16;
        if (c < H_) {
          const float v1 = acc1[mf][nf][q], v3 = acc3[mf][nf][q];
          hrow[c] = f2bf((v1 / (1.f + __expf(-v1))) * v3);
        }
      }
    }
#undef SA1
#undef SB1
#undef SB3
#undef LB
#undef LA
#undef MM
}

// =====================================================================
// GEMM2 (2 phases/tile x 16 MFMA): y[tok,:] (+)= w * (h @ W2t)
// K = 2752 -> 43 real + 1 zero tile = 44. LDS: A 64KB + B 32KB = 96KB.
// Same swizzle/staging geometry. VMC(3)/VMC(2) checkpoints.
// =====================================================================
template<int MODE>   // 0: shared (plain store), 1: routed (atomicAdd * w)
__global__ __launch_bounds__(512, 2) void gemm2_2p(
    const u16* __restrict__ hbuf, const u16* __restrict__ w2t_all,
    float* __restrict__ y, const int* __restrict__ offsets,
    const int* __restrict__ ptok, const float* __restrict__ pw,
    const char* __restrict__ zp)
{
  __shared__ char lds[98304];
  const int t = threadIdx.x;
  const int bx = blockIdx.x;
  const int n0 = blockIdx.y * 128;

  int row0 = bx * 256; size_t hr0; const u16* bW;
  if (MODE == 1) {
    if (row0 >= offsets[8]) return;
    int e = 0;
#pragma unroll
    for (int i = 0; i < 7; ++i) if (row0 >= offsets[i + 1]) e = i + 1;
    bW = w2t_all + (size_t)e * (C_ * H_);
    hr0 = (size_t)row0;
  } else {
    bW = w2t_all;
    hr0 = (size_t)SHARED_HBASE + row0;
  }

  const int sr = t >> 3;
  const int scb = (((t & 7) ^ (sr & 7)) << 4);
  const char* aS[4]; const char* bS[2];
#pragma unroll
  for (int c = 0; c < 4; ++c)
    aS[c] = (const char*)hbuf + (hr0 + c * 64 + sr) * (size_t)(H_ * 2) + scb;
#pragma unroll
  for (int c = 0; c < 2; ++c)
    bS[c] = (const char*)bW + (size_t)(n0 + c * 64 + sr) * (H_ * 2) + scb;
  const int wb = (t >> 6) << 10;
  char* ldsp = (char*)lds;
  const char* zpa = zp + t * 16;

#define SA2(kt,c) do { const char* s_ = ((kt) < 43) ? (aS[c] + (kt)*128) : zpa; \
  gld16(s_, ldsp + ((kt)&1)*32768 + (c)*8192 + wb); } while (0)
#define SB2(kt,c) do { const char* s_ = ((kt) < 43) ? (bS[c] + (kt)*128) : zpa; \
  gld16(s_, ldsp + 65536 + ((kt)&1)*16384 + (c)*8192 + wb); } while (0)

  const int lane = t & 63, l15 = lane & 15, lhi = lane >> 4;
  const int wv = t >> 6, wm = wv >> 2, wn = wv & 3;
  const int co0 = ((lhi ^ (l15 & 7)) << 4);
  const int co1 = (((4 + lhi) ^ (l15 & 7)) << 4);
  const int arow = wm * 16384 + l15 * 128;
  const int brow = wn * 4096 + l15 * 128;

  bf16x8 a[4][2], rb[2][2];
  f32x4 acc[8][2];
#pragma unroll
  for (int i = 0; i < 8; ++i)
#pragma unroll
    for (int j = 0; j < 2; ++j) acc[i][j] = f32x4{0,0,0,0};

#define LB2(p) do { _Pragma("unroll") for (int nf = 0; nf < 2; ++nf) { \
  rb[nf][0] = *(const bf16x8*)(ldsp + 65536 + (p)*16384 + brow + nf*2048 + co0); \
  rb[nf][1] = *(const bf16x8*)(ldsp + 65536 + (p)*16384 + brow + nf*2048 + co1); } } while (0)
#define LA2(p,mh) do { _Pragma("unroll") for (int mf = 0; mf < 4; ++mf) { \
  a[mf][0] = *(const bf16x8*)(ldsp + (p)*32768 + arow + ((mh)*4+mf)*2048 + co0); \
  a[mf][1] = *(const bf16x8*)(ldsp + (p)*32768 + arow + ((mh)*4+mf)*2048 + co1); } } while (0)
#define MM2(mh) do { __builtin_amdgcn_s_setprio(1); \
  _Pragma("unroll") for (int kh = 0; kh < 2; ++kh) \
    _Pragma("unroll") for (int mf = 0; mf < 4; ++mf) \
      _Pragma("unroll") for (int nf = 0; nf < 2; ++nf) \
        acc[(mh)*4+mf][nf] = MFMA16(a[mf][kh], rb[nf][kh], acc[(mh)*4+mf][nf]); \
  __builtin_amdgcn_s_setprio(0); } while (0)

  // prologue: tile 0, need-order A0,A2,B0,B1,A1,A3
  SA2(0,0); SA2(0,2); SB2(0,0); SB2(0,1); SA2(0,1); SA2(0,3);
  VMC(2); BARX();

#pragma unroll 1
  for (int j = 0; j < 44; ++j) {
    const int p = j & 1;
    const bool more = (j < 43);
    // ph0: mh0
    LB2(p); LA2(p, 0);
    if (more) { SA2(j+1,0); SA2(j+1,2); SB2(j+1,0); }
    BARX(); MM2(0);
    if (more) { VMC(3); } else { VMC(0); }
    BARX();
    // ph1: mh1
    LA2(p, 1);
    if (more) { SB2(j+1,1); SA2(j+1,1); SA2(j+1,3); }
    BARX(); MM2(1);
    if (more) { VMC(2); }
    BARX();
  }

  // epilogue
  const int rb_ = wm * 128 + lhi * 4;
  const int cb_ = n0 + wn * 32 + l15;
#pragma unroll
  for (int mf = 0; mf < 8; ++mf)
#pragma unroll
    for (int q = 0; q < 4; ++q) {
      const int r = rb_ + mf * 16 + q;
      if (MODE == 0) {
        float* yr = y + (size_t)(row0 + r) * C_;
#pragma unroll
        for (int nf = 0; nf < 2; ++nf) yr[cb_ + nf * 16] = acc[mf][nf][q];
      } else {
        const float wgt = pw[row0 + r];
        if (wgt != 0.f) {
          const int tok = ptok[row0 + r];
          float* yr = y + (size_t)tok * C_;
#pragma unroll
          for (int nf = 0; nf < 2; ++nf)
            atomicAdd(yr + cb_ + nf * 16, wgt * acc[mf][nf][q]);
        }
      }
    }
#undef SA2
#undef SB2
#undef LB2
#undef LA2
#undef MM2
}

// ---------------- launch ----------------
extern "C" void kernel_launch(void* const* d_in, const int* in_sizes, int n_in,
                              void* d_out, int out_size, void* d_ws, size_t ws_size,
                              hipStream_t stream)
{
  const float* x    = (const float*)d_in[0];
  const float* gw   = (const float*)d_in[1];
  const float* bias = (const float*)d_in[2];
  const float* w1   = (const float*)d_in[3];
  const float* w2   = (const float*)d_in[4];
  const float* w3   = (const float*)d_in[5];
  const float* sw1  = (const float*)d_in[6];
  const float* sw2  = (const float*)d_in[7];
  const float* sw3  = (const float*)d_in[8];
  float* y = (float*)d_out;
  char* ws = (char*)d_ws;
  if (ws_size < WS_NEED) return;   // distinctive failure: output stays poisoned

  u16*   xb    = (u16*)(ws + OFF_XB);
  u16*   w1t   = (u16*)(ws + OFF_W1T);
  u16*   w3t   = (u16*)(ws + OFF_W3T);
  u16*   w2t   = (u16*)(ws + OFF_W2T);
  u16*   sw1t  = (u16*)(ws + OFF_SW1T);
  u16*   sw3t  = (u16*)(ws + OFF_SW3T);
  u16*   sw2t  = (u16*)(ws + OFF_SW2T);
  u16*   hbuf  = (u16*)(ws + OFF_H);
  char*  zp    = ws + OFF_ZP;
  int*   ridx  = (int*)(ws + OFF_RIDX);
  float* rwt   = (float*)(ws + OFF_RW);
  int*   offs  = (int*)(ws + OFF_OFFS);
  int*   ptok  = (int*)(ws + OFF_PTOK);
  float* pw    = (float*)(ws + OFF_PW);

  hipMemsetAsync(zp, 0, 16384, stream);
  gate_kernel<<<NTOK, 256, 0, stream>>>(x, gw, bias, xb, ridx, rwt);
  transpose_cs_kernel<<<dim3(H_ / 32, C_ / 32, 18), dim3(32, 8), 0, stream>>>(
      w1, w3, sw1, sw3, w1t, w3t, sw1t, sw3t);
  transpose_sc_kernel<<<dim3(C_ / 32, H_ / 32, 9), dim3(32, 8), 0, stream>>>(
      w2, sw2, w2t, sw2t);
  route_scan_kernel<<<1, 256, 0, stream>>>(ridx, rwt, offs, ptok, pw);

  // GEMM1: routed (bx<72) + shared (bx>=72) combined
  gemm1_2p<<<dim3(ROUTED_MB + SHARED_MB, 22), 512, 0, stream>>>(
      xb, w1t, w3t, sw1t, sw3t, hbuf, offs, ptok);
  // GEMM2: shared first (plain store initializes y), then routed atomics
  gemm2_2p<0><<<dim3(SHARED_MB, 8), 512, 0, stream>>>(
      hbuf, sw2t, y, offs, ptok, pw, zp);
  gemm2_2p<1><<<dim3(ROUTED_MB, 8), 512, 0, stream>>>(
      hbuf, w2t, y, offs, ptok, pw, zp);
}

// Round 5
// 732.214 us; speedup vs baseline: 1.0780x; 1.0780x over previous
//
#include <hip/hip_runtime.h>
#include <hip/hip_bf16.h>
#include <stdint.h>

// ---------------- problem constants ----------------
#define E_ 8
#define C_ 1024
#define H_ 2752
#define NTOK 8192            // B*T = 4*2048
#define CAP_ROWS 17408       // 16384 assignments + 8*128 pad, 128-aligned
#define ROUTED_XB1 136       // CAP_ROWS/128
#define SHARED_XB1 64        // NTOK/128
#define SHARED_HBASE 17408
#define HROWS 25600          // CAP_ROWS + NTOK

typedef unsigned short u16;
typedef __attribute__((ext_vector_type(8))) short bf16x8;    // 8 bf16 in 4 VGPRs
typedef __attribute__((ext_vector_type(16))) float f32x16;   // 32x32 accumulator

// ---------------- ws layout (bytes) ----------------
static constexpr size_t SZ_XB    = (size_t)NTOK * C_ * 2;
static constexpr size_t SZ_WT    = (size_t)E_ * H_ * C_ * 2;
static constexpr size_t SZ_SWT   = (size_t)H_ * C_ * 2;
static constexpr size_t SZ_H     = (size_t)HROWS * H_ * 2;

static constexpr size_t OFF_XB   = 0;
static constexpr size_t OFF_W1T  = OFF_XB   + SZ_XB;
static constexpr size_t OFF_W3T  = OFF_W1T  + SZ_WT;
static constexpr size_t OFF_W2T  = OFF_W3T  + SZ_WT;
static constexpr size_t OFF_SW1T = OFF_W2T  + SZ_WT;
static constexpr size_t OFF_SW3T = OFF_SW1T + SZ_SWT;
static constexpr size_t OFF_SW2T = OFF_SW3T + SZ_SWT;
static constexpr size_t OFF_H    = OFF_SW2T + SZ_SWT;
static constexpr size_t OFF_RIDX = OFF_H    + SZ_H;                 // int[NTOK*2]
static constexpr size_t OFF_RW   = OFF_RIDX + (size_t)NTOK*2*4;     // float[NTOK*2]
static constexpr size_t OFF_OFFS = OFF_RW   + (size_t)NTOK*2*4;     // int[16]
static constexpr size_t OFF_PTOK = OFF_OFFS + 64;                   // int[CAP_ROWS]
static constexpr size_t OFF_PW   = OFF_PTOK + (size_t)CAP_ROWS*4;   // float[CAP_ROWS]
static constexpr size_t WS_NEED  = OFF_PW   + (size_t)CAP_ROWS*4;

// ---------------- helpers ----------------
__device__ __forceinline__ u16 f2bf(float f) {
  union { float f; uint32_t u; } v; v.f = f;
  uint32_t r = v.u + 0x7FFFu + ((v.u >> 16) & 1u);   // RNE
  return (u16)(r >> 16);
}

// async global->LDS, 16B per lane; LDS base wave-uniform, lane offset automatic.
__device__ __forceinline__ void gld16(const void* g, void* l) {
  uint32_t lo = (uint32_t)(uintptr_t)l;
  lo = __builtin_amdgcn_readfirstlane(lo);
  __builtin_amdgcn_global_load_lds(
      (const __attribute__((address_space(1))) void*)g,
      (__attribute__((address_space(3))) void*)(uintptr_t)lo, 16, 0, 0);
}

#define MFMA32(A,B,C) __builtin_amdgcn_mfma_f32_32x32x16_bf16((A),(B),(C),0,0,0)

// ---------------- gating: fp32 scores, top-2, plus x->bf16 ----------------
__global__ __launch_bounds__(256) void gate_kernel(
    const float* __restrict__ x, const float* __restrict__ gw,
    const float* __restrict__ bias, u16* __restrict__ xb,
    int* __restrict__ ridx, float* __restrict__ rw)
{
  const int n = blockIdx.x, t = threadIdx.x;
  const float4 v = *(const float4*)(x + (size_t)n * C_ + t * 4);
  union { u16 u[4]; uint2 d; } pk;
  pk.u[0] = f2bf(v.x); pk.u[1] = f2bf(v.y); pk.u[2] = f2bf(v.z); pk.u[3] = f2bf(v.w);
  *(uint2*)(xb + (size_t)n * C_ + t * 4) = pk.d;

  float p[E_];
#pragma unroll
  for (int e = 0; e < E_; ++e) {
    const float4 g = *(const float4*)(gw + (size_t)e * C_ + t * 4);
    p[e] = v.x * g.x + v.y * g.y + v.z * g.z + v.w * g.w;
  }
#pragma unroll
  for (int e = 0; e < E_; ++e)
    for (int off = 32; off > 0; off >>= 1) p[e] += __shfl_down(p[e], off);

  __shared__ float red[4][E_];
  const int wv = t >> 6;
  if ((t & 63) == 0) {
#pragma unroll
    for (int e = 0; e < E_; ++e) red[wv][e] = p[e];
  }
  __syncthreads();
  if (t == 0) {
    float sc[E_], rt[E_];
#pragma unroll
    for (int e = 0; e < E_; ++e) {
      const float d = red[0][e] + red[1][e] + red[2][e] + red[3][e];
      const float s = 1.f / (1.f + expf(-d));
      sc[e] = s; rt[e] = s + bias[e];
    }
    int i0 = 0; float b0 = rt[0];
#pragma unroll
    for (int e = 1; e < E_; ++e) if (rt[e] > b0) { b0 = rt[e]; i0 = e; }
    int i1 = -1; float b1 = -1e30f;
#pragma unroll
    for (int e = 0; e < E_; ++e) if (e != i0 && rt[e] > b1) { b1 = rt[e]; i1 = e; }
    const float s0 = sc[i0], s1 = sc[i1];
    const float inv = 1.f / (s0 + s1 + 1e-8f);
    ridx[2 * n] = i0; ridx[2 * n + 1] = i1;
    rw[2 * n] = s0 * inv; rw[2 * n + 1] = s1 * inv;
  }
}

// ---------------- weight transpose + fp32->bf16 ----------------
__global__ __launch_bounds__(256) void transpose_cs_kernel(
    const float* __restrict__ w1, const float* __restrict__ w3,
    const float* __restrict__ sw1, const float* __restrict__ sw3,
    u16* __restrict__ w1t, u16* __restrict__ w3t,
    u16* __restrict__ sw1t, u16* __restrict__ sw3t)
{
  const int z = blockIdx.z;
  const float* src; u16* dst;
  if      (z < 8)  { src = w1 + (size_t)z * C_ * H_;       dst = w1t + (size_t)z * H_ * C_; }
  else if (z < 16) { src = w3 + (size_t)(z - 8) * C_ * H_; dst = w3t + (size_t)(z - 8) * H_ * C_; }
  else if (z == 16){ src = sw1; dst = sw1t; }
  else             { src = sw3; dst = sw3t; }
  __shared__ float tile[32][33];
  const int tx = threadIdx.x, ty = threadIdx.y;
  const int s0 = blockIdx.x * 32;   // H dim
  const int r0 = blockIdx.y * 32;   // C dim
#pragma unroll
  for (int i = 0; i < 4; ++i)
    tile[ty + 8 * i][tx] = src[(size_t)(r0 + ty + 8 * i) * H_ + s0 + tx];
  __syncthreads();
#pragma unroll
  for (int i = 0; i < 4; ++i)
    dst[(size_t)(s0 + ty + 8 * i) * C_ + r0 + tx] = f2bf(tile[tx][ty + 8 * i]);
}

__global__ __launch_bounds__(256) void transpose_sc_kernel(
    const float* __restrict__ w2, const float* __restrict__ sw2,
    u16* __restrict__ w2t, u16* __restrict__ sw2t)
{
  const int z = blockIdx.z;
  const float* src; u16* dst;
  if (z < 8) { src = w2 + (size_t)z * H_ * C_; dst = w2t + (size_t)z * C_ * H_; }
  else       { src = sw2; dst = sw2t; }
  __shared__ float tile[32][33];
  const int tx = threadIdx.x, ty = threadIdx.y;
  const int s0 = blockIdx.x * 32;   // C dim
  const int r0 = blockIdx.y * 32;   // H dim
#pragma unroll
  for (int i = 0; i < 4; ++i)
    tile[ty + 8 * i][tx] = src[(size_t)(r0 + ty + 8 * i) * C_ + s0 + tx];
  __syncthreads();
#pragma unroll
  for (int i = 0; i < 4; ++i)
    dst[(size_t)(s0 + ty + 8 * i) * H_ + r0 + tx] = f2bf(tile[tx][ty + 8 * i]);
}

// ---------------- deterministic routing scan/scatter (single block) ----------------
__global__ __launch_bounds__(256) void route_scan_kernel(
    const int* __restrict__ ridx, const float* __restrict__ rw,
    int* __restrict__ offsets, int* __restrict__ perm_tok, float* __restrict__ perm_w)
{
  __shared__ int cnt[256][E_];
  __shared__ int pref[E_][257];
  __shared__ int offs[E_ + 1];
  __shared__ int totals[E_];
  const int t = threadIdx.x;
#pragma unroll
  for (int e = 0; e < E_; ++e) cnt[t][e] = 0;
  for (int j = 0; j < 64; ++j) { const int e = ridx[t * 64 + j]; cnt[t][e]++; }
  __syncthreads();
  if (t < E_) {
    int run = 0;
    for (int i = 0; i < 256; ++i) { pref[t][i] = run; run += cnt[i][t]; }
    totals[t] = run; pref[t][256] = run;
  }
  __syncthreads();
  if (t == 0) {
    int o = 0;
    for (int e = 0; e < E_; ++e) { offs[e] = o; o += (totals[e] + 127) & ~127; }
    offs[E_] = o;
    for (int i = 0; i <= E_; ++i) offsets[i] = offs[i];
  }
  __syncthreads();
#pragma unroll
  for (int e = 0; e < E_; ++e) cnt[t][e] = offs[e] + pref[e][t];
  for (int j = 0; j < 64; ++j) {
    const int a = t * 64 + j;
    const int e = ridx[a];
    const int p = cnt[t][e]++;
    perm_tok[p] = a >> 1;
    perm_w[p] = rw[a];
  }
  __syncthreads();
  for (int e = 0; e < E_; ++e) {
    for (int p = offs[e] + totals[e] + t; p < offs[e + 1]; p += 256) {
      perm_tok[p] = 0; perm_w[p] = 0.f;     // pads: valid dummy row, zero weight
    }
  }
}

// =====================================================================
// GEMM1: h[row,:] = silu(x@W1) * (x@W3) -> bf16, 32x32x16 MFMA.
// 128x128 tile, BK=64 (128B rows), 4 waves (2Mx2N), wave-tile 64x64 dual.
// LDS: A | B1 | B3, each 128x64 bf16 = 16KB -> 48KB, single-buffered,
// 2-barrier loop (r1-proven structure, measured 0 bank conflicts).
// Swizzle: LDS[r][c16] = G[r][c16 ^ (r&7)]; read chunk (2*kk+hi) ^ (l&7).
// A-frag (32x16): row = l&31, k = (l>>5)*8 + j (k-contiguous b128).
// C/D frag: col = l&31, row = (q&3) + 8*(q>>2) + 4*(l>>5), q in [0,16).
// =====================================================================
__global__ __launch_bounds__(256, 2) void gemm1_32(
    const u16* __restrict__ xb, const u16* __restrict__ w1t_all,
    const u16* __restrict__ w3t_all, const u16* __restrict__ sw1t,
    const u16* __restrict__ sw3t, u16* __restrict__ hbuf,
    const int* __restrict__ offsets, const int* __restrict__ ptok)
{
  __shared__ char lds[49152];
  const int t = threadIdx.x;
  const int bx = blockIdx.x;
  const int n0 = blockIdx.y * 128;

  const u16 *b1w, *b3w; int row0; size_t hr0; int gather;
  if (bx < ROUTED_XB1) {
    row0 = bx * 128;
    if (row0 >= offsets[8]) return;
    int e = 0;
#pragma unroll
    for (int i = 0; i < 7; ++i) if (row0 >= offsets[i + 1]) e = i + 1;
    b1w = w1t_all + (size_t)e * (H_ * C_);
    b3w = w3t_all + (size_t)e * (H_ * C_);
    hr0 = (size_t)row0; gather = 1;
  } else {
    row0 = (bx - ROUTED_XB1) * 128;
    b1w = sw1t; b3w = sw3t; hr0 = (size_t)SHARED_HBASE + row0; gather = 0;
  }

  // staging: issue i covers rows i*32+tq (tq=t>>3), phys chunk t&7;
  // source chunk pre-swizzled: (t&7) ^ (tq&7)  [both-sides involution]
  const int tq = t >> 3;
  const int cb = (((t & 7) ^ (tq & 7)) << 4);
  const char* gA[4]; const char* gB1[4]; const char* gB3[4];
#pragma unroll
  for (int i = 0; i < 4; ++i) {
    const int m = i * 32 + tq;
    const int tok = gather ? ptok[row0 + m] : (row0 + m);
    gA[i] = (const char*)xb + (size_t)tok * 2048 + cb;
    int nn = n0 + m; if (nn > H_ - 1) nn = H_ - 1;   // N tail clamp
    gB1[i] = (const char*)b1w + (size_t)nn * 2048 + cb;
    gB3[i] = (const char*)b3w + (size_t)nn * 2048 + cb;
  }
  const int wvb = (t >> 6) << 10;
  char* ldsp = (char*)lds;

  const int lane = t & 63, l31 = lane & 31, hi = lane >> 5, x7 = lane & 7;
  const int wm = (t >> 7) & 1, wn = (t >> 6) & 1;
  int arow[2], brow[2];
#pragma unroll
  for (int f = 0; f < 2; ++f) {
    arow[f] = (wm * 64 + f * 32 + l31) * 128;
    brow[f] = (wn * 64 + f * 32 + l31) * 128;
  }

  f32x16 acc1[2][2], acc3[2][2];
#pragma unroll
  for (int i = 0; i < 2; ++i)
#pragma unroll
    for (int j = 0; j < 2; ++j) {
      acc1[i][j] = (f32x16)(0.f);
      acc3[i][j] = (f32x16)(0.f);
    }

  for (int kt = 0; kt < 16; ++kt) {
    const int kb = kt * 128;
#pragma unroll
    for (int i = 0; i < 4; ++i) gld16(gA[i]  + kb, ldsp + i * 4096 + wvb);
#pragma unroll
    for (int i = 0; i < 4; ++i) gld16(gB1[i] + kb, ldsp + 16384 + i * 4096 + wvb);
#pragma unroll
    for (int i = 0; i < 4; ++i) gld16(gB3[i] + kb, ldsp + 32768 + i * 4096 + wvb);
    __syncthreads();
#pragma unroll
    for (int kk = 0; kk < 4; ++kk) {
      const int co = (((2 * kk + hi) ^ x7) << 4);
      bf16x8 av[2], b1v[2], b3v[2];
#pragma unroll
      for (int f = 0; f < 2; ++f) av[f]  = *(const bf16x8*)(ldsp + arow[f] + co);
#pragma unroll
      for (int f = 0; f < 2; ++f) b1v[f] = *(const bf16x8*)(ldsp + 16384 + brow[f] + co);
#pragma unroll
      for (int f = 0; f < 2; ++f) b3v[f] = *(const bf16x8*)(ldsp + 32768 + brow[f] + co);
#pragma unroll
      for (int mf = 0; mf < 2; ++mf)
#pragma unroll
        for (int nf = 0; nf < 2; ++nf) {
          acc1[mf][nf] = MFMA32(av[mf], b1v[nf], acc1[mf][nf]);
          acc3[mf][nf] = MFMA32(av[mf], b3v[nf], acc3[mf][nf]);
        }
    }
    __syncthreads();
  }

  // epilogue: silu(acc1)*acc3 -> bf16 h
  const int cbase = n0 + wn * 64 + l31;
#pragma unroll
  for (int mf = 0; mf < 2; ++mf)
#pragma unroll
    for (int q = 0; q < 16; ++q) {
      const int r = wm * 64 + mf * 32 + (q & 3) + 8 * (q >> 2) + 4 * hi;
      u16* hrow = hbuf + (hr0 + r) * H_;
#pragma unroll
      for (int nf = 0; nf < 2; ++nf) {
        const int c = cbase + nf * 32;
        if (c < H_) {
          const float v1 = acc1[mf][nf][q], v3 = acc3[mf][nf][q];
          hrow[c] = f2bf((v1 / (1.f + __expf(-v1))) * v3);
        }
      }
    }
}

// =====================================================================
// GEMM2: y[tok,:] += w * (h[row,:] @ W2t), 32x32x16 MFMA, atomic combine.
// 128x128 tile, K = H = 2752 = 43 K-tiles exact. LDS 32KB -> 3+ blocks/CU.
// Covers routed rows (bx<136, weight pw) and shared rows (weight 1).
// =====================================================================
__global__ __launch_bounds__(256, 2) void gemm2_32(
    const u16* __restrict__ hbuf, const u16* __restrict__ w2t_all,
    const u16* __restrict__ sw2t, float* __restrict__ y,
    const int* __restrict__ offsets, const int* __restrict__ ptok,
    const float* __restrict__ pw)
{
  __shared__ char lds[32768];
  const int t = threadIdx.x;
  const int bx = blockIdx.x;
  const int n0 = blockIdx.y * 128;

  int row0; size_t hr0; const u16* bW; int routed;
  if (bx < ROUTED_XB1) {
    row0 = bx * 128;
    if (row0 >= offsets[8]) return;
    int e = 0;
#pragma unroll
    for (int i = 0; i < 7; ++i) if (row0 >= offsets[i + 1]) e = i + 1;
    bW = w2t_all + (size_t)e * (C_ * H_);
    hr0 = (size_t)row0; routed = 1;
  } else {
    row0 = (bx - ROUTED_XB1) * 128;
    bW = sw2t; hr0 = (size_t)SHARED_HBASE + row0; routed = 0;
  }

  const int tq = t >> 3;
  const int cb = (((t & 7) ^ (tq & 7)) << 4);
  const char* gA[4]; const char* gB[4];
#pragma unroll
  for (int i = 0; i < 4; ++i) {
    const int m = i * 32 + tq;
    gA[i] = (const char*)hbuf + (hr0 + m) * (size_t)(H_ * 2) + cb;
    gB[i] = (const char*)bW + (size_t)(n0 + m) * (H_ * 2) + cb;
  }
  const int wvb = (t >> 6) << 10;
  char* ldsp = (char*)lds;

  const int lane = t & 63, l31 = lane & 31, hi = lane >> 5, x7 = lane & 7;
  const int wm = (t >> 7) & 1, wn = (t >> 6) & 1;
  int arow[2], brow[2];
#pragma unroll
  for (int f = 0; f < 2; ++f) {
    arow[f] = (wm * 64 + f * 32 + l31) * 128;
    brow[f] = (wn * 64 + f * 32 + l31) * 128;
  }

  f32x16 acc[2][2];
#pragma unroll
  for (int i = 0; i < 2; ++i)
#pragma unroll
    for (int j = 0; j < 2; ++j) acc[i][j] = (f32x16)(0.f);

  for (int kt = 0; kt < 43; ++kt) {
    const int kb = kt * 128;
#pragma unroll
    for (int i = 0; i < 4; ++i) gld16(gA[i] + kb, ldsp + i * 4096 + wvb);
#pragma unroll
    for (int i = 0; i < 4; ++i) gld16(gB[i] + kb, ldsp + 16384 + i * 4096 + wvb);
    __syncthreads();
#pragma unroll
    for (int kk = 0; kk < 4; ++kk) {
      const int co = (((2 * kk + hi) ^ x7) << 4);
      bf16x8 av[2], bv[2];
#pragma unroll
      for (int f = 0; f < 2; ++f) av[f] = *(const bf16x8*)(ldsp + arow[f] + co);
#pragma unroll
      for (int f = 0; f < 2; ++f) bv[f] = *(const bf16x8*)(ldsp + 16384 + brow[f] + co);
#pragma unroll
      for (int mf = 0; mf < 2; ++mf)
#pragma unroll
        for (int nf = 0; nf < 2; ++nf)
          acc[mf][nf] = MFMA32(av[mf], bv[nf], acc[mf][nf]);
    }
    __syncthreads();
  }

  // epilogue: atomic combine into y (y pre-zeroed)
  const int cbase = n0 + wn * 64 + l31;
#pragma unroll
  for (int mf = 0; mf < 2; ++mf)
#pragma unroll
    for (int q = 0; q < 16; ++q) {
      const int r = wm * 64 + mf * 32 + (q & 3) + 8 * (q >> 2) + 4 * hi;
      const int hr = (int)hr0 + r;
      const float wgt = routed ? pw[hr] : 1.0f;
      if (wgt != 0.f) {
        const int tok = routed ? ptok[hr] : (hr - SHARED_HBASE);
        float* yr = y + (size_t)tok * C_;
#pragma unroll
        for (int nf = 0; nf < 2; ++nf)
          atomicAdd(yr + cbase + nf * 32, wgt * acc[mf][nf][q]);
      }
    }
}

// ---------------- launch ----------------
extern "C" void kernel_launch(void* const* d_in, const int* in_sizes, int n_in,
                              void* d_out, int out_size, void* d_ws, size_t ws_size,
                              hipStream_t stream)
{
  const float* x    = (const float*)d_in[0];
  const float* gw   = (const float*)d_in[1];
  const float* bias = (const float*)d_in[2];
  const float* w1   = (const float*)d_in[3];
  const float* w2   = (const float*)d_in[4];
  const float* w3   = (const float*)d_in[5];
  const float* sw1  = (const float*)d_in[6];
  const float* sw2  = (const float*)d_in[7];
  const float* sw3  = (const float*)d_in[8];
  float* y = (float*)d_out;
  char* ws = (char*)d_ws;
  if (ws_size < WS_NEED) return;   // distinctive failure: output stays poisoned

  u16*   xb    = (u16*)(ws + OFF_XB);
  u16*   w1t   = (u16*)(ws + OFF_W1T);
  u16*   w3t   = (u16*)(ws + OFF_W3T);
  u16*   w2t   = (u16*)(ws + OFF_W2T);
  u16*   sw1t  = (u16*)(ws + OFF_SW1T);
  u16*   sw3t  = (u16*)(ws + OFF_SW3T);
  u16*   sw2t  = (u16*)(ws + OFF_SW2T);
  u16*   hbuf  = (u16*)(ws + OFF_H);
  int*   ridx  = (int*)(ws + OFF_RIDX);
  float* rwt   = (float*)(ws + OFF_RW);
  int*   offs  = (int*)(ws + OFF_OFFS);
  int*   ptok  = (int*)(ws + OFF_PTOK);
  float* pw    = (float*)(ws + OFF_PW);

  hipMemsetAsync(y, 0, (size_t)out_size * 4, stream);
  gate_kernel<<<NTOK, 256, 0, stream>>>(x, gw, bias, xb, ridx, rwt);
  transpose_cs_kernel<<<dim3(H_ / 32, C_ / 32, 18), dim3(32, 8), 0, stream>>>(
      w1, w3, sw1, sw3, w1t, w3t, sw1t, sw3t);
  transpose_sc_kernel<<<dim3(C_ / 32, H_ / 32, 9), dim3(32, 8), 0, stream>>>(
      w2, sw2, w2t, sw2t);
  route_scan_kernel<<<1, 256, 0, stream>>>(ridx, rwt, offs, ptok, pw);

  // GEMM1: routed (bx<136) + shared (bx>=136) in one dispatch
  gemm1_32<<<dim3(ROUTED_XB1 + SHARED_XB1, 22), 256, 0, stream>>>(
      xb, w1t, w3t, sw1t, sw3t, hbuf, offs, ptok);
  // GEMM2: one atomic dispatch over routed + shared rows (y pre-zeroed)
  gemm2_32<<<dim3(ROUTED_XB1 + SHARED_XB1, 8), 256, 0, stream>>>(
      hbuf, w2t, sw2t, y, offs, ptok, pw);
}

// Round 6
// 695.441 us; speedup vs baseline: 1.1350x; 1.0529x over previous
//
#include <hip/hip_runtime.h>
#include <hip/hip_bf16.h>
#include <stdint.h>

// ---------------- problem constants ----------------
#define E_ 8
#define C_ 1024
#define H_ 2752
#define NTOK 8192            // B*T = 4*2048
#define CAP_ROWS 17408       // 16384 assignments + 8*128 pad, 128-aligned
#define ROUTED_XB 136        // CAP_ROWS/128
#define SHARED_XB 64         // NTOK/128
#define SHARED_HBASE 17408
#define HROWS 25600          // CAP_ROWS + NTOK

typedef unsigned short u16;
typedef __attribute__((ext_vector_type(8))) short bf16x8;   // 8 bf16 in 4 VGPRs
typedef __attribute__((ext_vector_type(4))) float f32x4;

// ---------------- ws layout (bytes) ----------------
static constexpr size_t SZ_XB    = (size_t)NTOK * C_ * 2;
static constexpr size_t SZ_WT    = (size_t)E_ * H_ * C_ * 2;
static constexpr size_t SZ_SWT   = (size_t)H_ * C_ * 2;
static constexpr size_t SZ_H     = (size_t)HROWS * H_ * 2;

static constexpr size_t OFF_XB   = 0;
static constexpr size_t OFF_W1T  = OFF_XB   + SZ_XB;
static constexpr size_t OFF_W3T  = OFF_W1T  + SZ_WT;
static constexpr size_t OFF_W2T  = OFF_W3T  + SZ_WT;
static constexpr size_t OFF_SW1T = OFF_W2T  + SZ_WT;
static constexpr size_t OFF_SW3T = OFF_SW1T + SZ_SWT;
static constexpr size_t OFF_SW2T = OFF_SW3T + SZ_SWT;
static constexpr size_t OFF_H    = OFF_SW2T + SZ_SWT;
static constexpr size_t OFF_RIDX = OFF_H    + SZ_H;                 // int[NTOK*2]
static constexpr size_t OFF_RW   = OFF_RIDX + (size_t)NTOK*2*4;     // float[NTOK*2]
static constexpr size_t OFF_OFFS = OFF_RW   + (size_t)NTOK*2*4;     // int[16]
static constexpr size_t OFF_PTOK = OFF_OFFS + 64;                   // int[CAP_ROWS]
static constexpr size_t OFF_PW   = OFF_PTOK + (size_t)CAP_ROWS*4;   // float[CAP_ROWS]
static constexpr size_t WS_NEED  = OFF_PW   + (size_t)CAP_ROWS*4;

// ---------------- helpers ----------------
__device__ __forceinline__ u16 f2bf(float f) {
  union { float f; uint32_t u; } v; v.f = f;
  uint32_t r = v.u + 0x7FFFu + ((v.u >> 16) & 1u);   // RNE
  return (u16)(r >> 16);
}

// async global->LDS, 16B per lane; LDS base wave-uniform, lane offset automatic.
__device__ __forceinline__ void gld16(const void* g, void* l) {
  uint32_t lo = (uint32_t)(uintptr_t)l;
  lo = __builtin_amdgcn_readfirstlane(lo);
  __builtin_amdgcn_global_load_lds(
      (const __attribute__((address_space(1))) void*)g,
      (__attribute__((address_space(3))) void*)(uintptr_t)lo, 16, 0, 0);
}

#define MFMA16(A,B,C) __builtin_amdgcn_mfma_f32_16x16x32_bf16((A),(B),(C),0,0,0)

// ---------------- gating: fp32 scores, top-2, plus x->bf16 ----------------
__global__ __launch_bounds__(256) void gate_kernel(
    const float* __restrict__ x, const float* __restrict__ gw,
    const float* __restrict__ bias, u16* __restrict__ xb,
    int* __restrict__ ridx, float* __restrict__ rw)
{
  const int n = blockIdx.x, t = threadIdx.x;
  const float4 v = *(const float4*)(x + (size_t)n * C_ + t * 4);
  union { u16 u[4]; uint2 d; } pk;
  pk.u[0] = f2bf(v.x); pk.u[1] = f2bf(v.y); pk.u[2] = f2bf(v.z); pk.u[3] = f2bf(v.w);
  *(uint2*)(xb + (size_t)n * C_ + t * 4) = pk.d;

  float p[E_];
#pragma unroll
  for (int e = 0; e < E_; ++e) {
    const float4 g = *(const float4*)(gw + (size_t)e * C_ + t * 4);
    p[e] = v.x * g.x + v.y * g.y + v.z * g.z + v.w * g.w;
  }
#pragma unroll
  for (int e = 0; e < E_; ++e)
    for (int off = 32; off > 0; off >>= 1) p[e] += __shfl_down(p[e], off);

  __shared__ float red[4][E_];
  const int wv = t >> 6;
  if ((t & 63) == 0) {
#pragma unroll
    for (int e = 0; e < E_; ++e) red[wv][e] = p[e];
  }
  __syncthreads();
  if (t == 0) {
    float sc[E_], rt[E_];
#pragma unroll
    for (int e = 0; e < E_; ++e) {
      const float d = red[0][e] + red[1][e] + red[2][e] + red[3][e];
      const float s = 1.f / (1.f + expf(-d));
      sc[e] = s; rt[e] = s + bias[e];
    }
    int i0 = 0; float b0 = rt[0];
#pragma unroll
    for (int e = 1; e < E_; ++e) if (rt[e] > b0) { b0 = rt[e]; i0 = e; }
    int i1 = -1; float b1 = -1e30f;
#pragma unroll
    for (int e = 0; e < E_; ++e) if (e != i0 && rt[e] > b1) { b1 = rt[e]; i1 = e; }
    const float s0 = sc[i0], s1 = sc[i1];
    const float inv = 1.f / (s0 + s1 + 1e-8f);
    ridx[2 * n] = i0; ridx[2 * n + 1] = i1;
    rw[2 * n] = s0 * inv; rw[2 * n + 1] = s1 * inv;
  }
}

// ---------------- weight transpose + fp32->bf16 ----------------
__global__ __launch_bounds__(256) void transpose_cs_kernel(
    const float* __restrict__ w1, const float* __restrict__ w3,
    const float* __restrict__ sw1, const float* __restrict__ sw3,
    u16* __restrict__ w1t, u16* __restrict__ w3t,
    u16* __restrict__ sw1t, u16* __restrict__ sw3t)
{
  const int z = blockIdx.z;
  const float* src; u16* dst;
  if      (z < 8)  { src = w1 + (size_t)z * C_ * H_;       dst = w1t + (size_t)z * H_ * C_; }
  else if (z < 16) { src = w3 + (size_t)(z - 8) * C_ * H_; dst = w3t + (size_t)(z - 8) * H_ * C_; }
  else if (z == 16){ src = sw1; dst = sw1t; }
  else             { src = sw3; dst = sw3t; }
  __shared__ float tile[32][33];
  const int tx = threadIdx.x, ty = threadIdx.y;
  const int s0 = blockIdx.x * 32;   // H dim
  const int r0 = blockIdx.y * 32;   // C dim
#pragma unroll
  for (int i = 0; i < 4; ++i)
    tile[ty + 8 * i][tx] = src[(size_t)(r0 + ty + 8 * i) * H_ + s0 + tx];
  __syncthreads();
#pragma unroll
  for (int i = 0; i < 4; ++i)
    dst[(size_t)(s0 + ty + 8 * i) * C_ + r0 + tx] = f2bf(tile[tx][ty + 8 * i]);
}

__global__ __launch_bounds__(256) void transpose_sc_kernel(
    const float* __restrict__ w2, const float* __restrict__ sw2,
    u16* __restrict__ w2t, u16* __restrict__ sw2t)
{
  const int z = blockIdx.z;
  const float* src; u16* dst;
  if (z < 8) { src = w2 + (size_t)z * H_ * C_; dst = w2t + (size_t)z * C_ * H_; }
  else       { src = sw2; dst = sw2t; }
  __shared__ float tile[32][33];
  const int tx = threadIdx.x, ty = threadIdx.y;
  const int s0 = blockIdx.x * 32;   // C dim
  const int r0 = blockIdx.y * 32;   // H dim
#pragma unroll
  for (int i = 0; i < 4; ++i)
    tile[ty + 8 * i][tx] = src[(size_t)(r0 + ty + 8 * i) * C_ + s0 + tx];
  __syncthreads();
#pragma unroll
  for (int i = 0; i < 4; ++i)
    dst[(size_t)(s0 + ty + 8 * i) * H_ + r0 + tx] = f2bf(tile[tx][ty + 8 * i]);
}

// ---------------- deterministic routing scan/scatter (single block) ----------------
__global__ __launch_bounds__(256) void route_scan_kernel(
    const int* __restrict__ ridx, const float* __restrict__ rw,
    int* __restrict__ offsets, int* __restrict__ perm_tok, float* __restrict__ perm_w)
{
  __shared__ int cnt[256][E_];
  __shared__ int pref[E_][257];
  __shared__ int offs[E_ + 1];
  __shared__ int totals[E_];
  const int t = threadIdx.x;
#pragma unroll
  for (int e = 0; e < E_; ++e) cnt[t][e] = 0;
  for (int j = 0; j < 64; ++j) { const int e = ridx[t * 64 + j]; cnt[t][e]++; }
  __syncthreads();
  if (t < E_) {
    int run = 0;
    for (int i = 0; i < 256; ++i) { pref[t][i] = run; run += cnt[i][t]; }
    totals[t] = run; pref[t][256] = run;
  }
  __syncthreads();
  if (t == 0) {
    int o = 0;
    for (int e = 0; e < E_; ++e) { offs[e] = o; o += (totals[e] + 127) & ~127; }
    offs[E_] = o;
    for (int i = 0; i <= E_; ++i) offsets[i] = offs[i];
  }
  __syncthreads();
#pragma unroll
  for (int e = 0; e < E_; ++e) cnt[t][e] = offs[e] + pref[e][t];
  for (int j = 0; j < 64; ++j) {
    const int a = t * 64 + j;
    const int e = ridx[a];
    const int p = cnt[t][e]++;
    perm_tok[p] = a >> 1;
    perm_w[p] = rw[a];
  }
  __syncthreads();
  for (int e = 0; e < E_; ++e) {
    for (int p = offs[e] + totals[e] + t; p < offs[e + 1]; p += 256) {
      perm_tok[p] = 0; perm_w[p] = 0.f;     // pads: valid dummy row, zero weight
    }
  }
}

// =====================================================================
// GEMM1 (r1-proven inner loop, merged routed+shared):
// h[row,:] = silu(x@W1) * (x@W3) -> bf16.  128x128 tile, BK=64, 4 waves,
// 16x16x32 MFMA, dual-B accumulators, 2-barrier loop, 48KB LDS.
// Swizzle (measured 0 conflicts): LDS[r][c16] = G[r][c16 ^ (r&7)];
// read chunk = ((kk<<2)|lhi) ^ (l15&7).
// =====================================================================
__global__ __launch_bounds__(256, 2) void gemm1_m(
    const u16* __restrict__ xb, const u16* __restrict__ w1t_all,
    const u16* __restrict__ w3t_all, const u16* __restrict__ sw1t,
    const u16* __restrict__ sw3t, u16* __restrict__ hbuf,
    const int* __restrict__ offsets, const int* __restrict__ ptok)
{
  __shared__ u16 lds[3 * 8192];   // A | B1 | B3, each 128x64 bf16 (16KB)
  const int t = threadIdx.x;
  const int bx = blockIdx.x;
  const int n0 = blockIdx.y * 128;

  const u16 *b1w, *b3w; int row0; size_t hr0; int gather;
  if (bx < ROUTED_XB) {
    row0 = bx * 128;
    if (row0 >= offsets[8]) return;
    int e = 0;
#pragma unroll
    for (int i = 0; i < 7; ++i) if (row0 >= offsets[i + 1]) e = i + 1;
    b1w = w1t_all + (size_t)e * (H_ * C_);
    b3w = w3t_all + (size_t)e * (H_ * C_);
    hr0 = (size_t)row0; gather = 1;
  } else {
    row0 = (bx - ROUTED_XB) * 128;
    b1w = sw1t; b3w = sw3t; hr0 = (size_t)SHARED_HBASE + row0; gather = 0;
  }

  // staging: thread t, issue i covers LDS row m=i*32+(t>>3), phys chunk t&7;
  // source chunk pre-swizzled so XOR-swizzled ds_read is conflict-free.
  const int tq = t >> 3;
  const int cb = (((t & 7) ^ (tq & 7)) << 4);
  const char* gA[4]; const char* gB1[4]; const char* gB3[4];
#pragma unroll
  for (int i = 0; i < 4; ++i) {
    const int m = i * 32 + tq;
    const int tok = gather ? ptok[row0 + m] : (row0 + m);
    gA[i] = (const char*)xb + (size_t)tok * (C_ * 2) + cb;
    int nn = n0 + m; if (nn > H_ - 1) nn = H_ - 1;    // N tail clamp
    gB1[i] = (const char*)b1w + (size_t)nn * (C_ * 2) + cb;
    gB3[i] = (const char*)b3w + (size_t)nn * (C_ * 2) + cb;
  }
  char* lwave = (char*)lds + (t >> 6) * 1024;

  f32x4 acc1[4][4], acc3[4][4];
#pragma unroll
  for (int i = 0; i < 4; ++i)
#pragma unroll
    for (int j = 0; j < 4; ++j) { acc1[i][j] = f32x4{0,0,0,0}; acc3[i][j] = f32x4{0,0,0,0}; }

  const int lane = t & 63;
  const int l15 = lane & 15, lhi = lane >> 4, swz = lane & 7;
  const int wm = (t >> 7) & 1, wn = (t >> 6) & 1;
  int arow[4], brow[4];
#pragma unroll
  for (int f = 0; f < 4; ++f) {
    arow[f] = (wm * 64 + f * 16 + l15) * 128;
    brow[f] = (wn * 64 + f * 16 + l15) * 128;
  }
  const char* ldsc = (const char*)lds;

  for (int kt = 0; kt < C_ / 64; ++kt) {
    const int kb = kt * 128;
#pragma unroll
    for (int i = 0; i < 4; ++i) gld16(gA[i]  + kb, lwave + i * 4096);
#pragma unroll
    for (int i = 0; i < 4; ++i) gld16(gB1[i] + kb, lwave + 16384 + i * 4096);
#pragma unroll
    for (int i = 0; i < 4; ++i) gld16(gB3[i] + kb, lwave + 32768 + i * 4096);
    __syncthreads();
#pragma unroll
    for (int kk = 0; kk < 2; ++kk) {
      const int co = ((((kk << 2) | lhi)) ^ swz) << 4;
      bf16x8 a[4], b1[4], b3[4];
#pragma unroll
      for (int f = 0; f < 4; ++f) a[f]  = *(const bf16x8*)(ldsc + arow[f] + co);
#pragma unroll
      for (int f = 0; f < 4; ++f) b1[f] = *(const bf16x8*)(ldsc + 16384 + brow[f] + co);
#pragma unroll
      for (int f = 0; f < 4; ++f) b3[f] = *(const bf16x8*)(ldsc + 32768 + brow[f] + co);
#pragma unroll
      for (int mf = 0; mf < 4; ++mf)
#pragma unroll
        for (int nf = 0; nf < 4; ++nf) {
          acc1[mf][nf] = MFMA16(a[mf], b1[nf], acc1[mf][nf]);
          acc3[mf][nf] = MFMA16(a[mf], b3[nf], acc3[mf][nf]);
        }
    }
    __syncthreads();
  }

  // epilogue: silu(h1)*h3 -> bf16. C/D map: row=(lane>>4)*4+reg, col=lane&15
  const int rbase = wm * 64 + lhi * 4;
  const int cbase = n0 + wn * 64 + l15;
#pragma unroll
  for (int mf = 0; mf < 4; ++mf)
#pragma unroll
    for (int q = 0; q < 4; ++q) {
      const int r = rbase + mf * 16 + q;
      u16* hrow = hbuf + (hr0 + r) * H_;
#pragma unroll
      for (int nf = 0; nf < 4; ++nf) {
        const int c = cbase + nf * 16;
        if (c < H_) {
          const float v1 = acc1[mf][nf][q], v3 = acc3[mf][nf][q];
          const float sv = v1 / (1.f + __expf(-v1));
          hrow[c] = f2bf(sv * v3);
        }
      }
    }
}

// =====================================================================
// GEMM2 (r1-proven inner loop, merged all-atomic over pre-zeroed y):
// y[tok,:] += w * (h[row,:] @ W2t). 128x128 tile, K = 2752 = 43 exact
// K-tiles, 32KB LDS. Routed rows use pw/ptok; shared rows weight 1.
// =====================================================================
__global__ __launch_bounds__(256, 2) void gemm2_m(
    const u16* __restrict__ hbuf, const u16* __restrict__ w2t_all,
    const u16* __restrict__ sw2t, float* __restrict__ y,
    const int* __restrict__ offsets, const int* __restrict__ ptok,
    const float* __restrict__ pw)
{
  __shared__ u16 lds[2 * 8192];
  const int t = threadIdx.x;
  const int bx = blockIdx.x;
  const int n0 = blockIdx.y * 128;

  int row0; size_t hr0; const u16* bW; int routed;
  if (bx < ROUTED_XB) {
    row0 = bx * 128;
    if (row0 >= offsets[8]) return;
    int e = 0;
#pragma unroll
    for (int i = 0; i < 7; ++i) if (row0 >= offsets[i + 1]) e = i + 1;
    bW = w2t_all + (size_t)e * (C_ * H_);
    hr0 = (size_t)row0; routed = 1;
  } else {
    row0 = (bx - ROUTED_XB) * 128;
    bW = sw2t; hr0 = (size_t)SHARED_HBASE + row0; routed = 0;
  }

  const int tq = t >> 3;
  const int cb = (((t & 7) ^ (tq & 7)) << 4);
  const char* gA[4]; const char* gB[4];
#pragma unroll
  for (int i = 0; i < 4; ++i) {
    const int m = i * 32 + tq;
    gA[i] = (const char*)hbuf + (hr0 + m) * (size_t)(H_ * 2) + cb;
    gB[i] = (const char*)bW + (size_t)(n0 + m) * (H_ * 2) + cb;
  }
  char* lwave = (char*)lds + (t >> 6) * 1024;

  f32x4 acc[4][4];
#pragma unroll
  for (int i = 0; i < 4; ++i)
#pragma unroll
    for (int j = 0; j < 4; ++j) acc[i][j] = f32x4{0,0,0,0};

  const int lane = t & 63;
  const int l15 = lane & 15, lhi = lane >> 4, swz = lane & 7;
  const int wm = (t >> 7) & 1, wn = (t >> 6) & 1;
  int arow[4], brow[4];
#pragma unroll
  for (int f = 0; f < 4; ++f) {
    arow[f] = (wm * 64 + f * 16 + l15) * 128;
    brow[f] = (wn * 64 + f * 16 + l15) * 128;
  }
  const char* ldsc = (const char*)lds;

  for (int kt = 0; kt < 43; ++kt) {   // K = 2752, exact
    const int kb = kt * 128;
#pragma unroll
    for (int i = 0; i < 4; ++i) gld16(gA[i] + kb, lwave + i * 4096);
#pragma unroll
    for (int i = 0; i < 4; ++i) gld16(gB[i] + kb, lwave + 16384 + i * 4096);
    __syncthreads();
#pragma unroll
    for (int kk = 0; kk < 2; ++kk) {
      const int co = ((((kk << 2) | lhi)) ^ swz) << 4;
      bf16x8 a[4], b[4];
#pragma unroll
      for (int f = 0; f < 4; ++f) a[f] = *(const bf16x8*)(ldsc + arow[f] + co);
#pragma unroll
      for (int f = 0; f < 4; ++f) b[f] = *(const bf16x8*)(ldsc + 16384 + brow[f] + co);
#pragma unroll
      for (int mf = 0; mf < 4; ++mf)
#pragma unroll
        for (int nf = 0; nf < 4; ++nf)
          acc[mf][nf] = MFMA16(a[mf], b[nf], acc[mf][nf]);
    }
    __syncthreads();
  }

  // epilogue: atomic combine into pre-zeroed y
  const int rbase = wm * 64 + lhi * 4;
  const int cbase = n0 + wn * 64 + l15;
#pragma unroll
  for (int mf = 0; mf < 4; ++mf)
#pragma unroll
    for (int q = 0; q < 4; ++q) {
      const int hr = (int)hr0 + rbase + mf * 16 + q;
      const float wgt = routed ? pw[hr] : 1.0f;
      if (wgt != 0.f) {
        const int tok = routed ? ptok[hr] : (hr - SHARED_HBASE);
        float* yr = y + (size_t)tok * C_;
#pragma unroll
        for (int nf = 0; nf < 4; ++nf)
          atomicAdd(yr + cbase + nf * 16, wgt * acc[mf][nf][q]);
      }
    }
}

// ---------------- launch ----------------
extern "C" void kernel_launch(void* const* d_in, const int* in_sizes, int n_in,
                              void* d_out, int out_size, void* d_ws, size_t ws_size,
                              hipStream_t stream)
{
  const float* x    = (const float*)d_in[0];
  const float* gw   = (const float*)d_in[1];
  const float* bias = (const float*)d_in[2];
  const float* w1   = (const float*)d_in[3];
  const float* w2   = (const float*)d_in[4];
  const float* w3   = (const float*)d_in[5];
  const float* sw1  = (const float*)d_in[6];
  const float* sw2  = (const float*)d_in[7];
  const float* sw3  = (const float*)d_in[8];
  float* y = (float*)d_out;
  char* ws = (char*)d_ws;
  if (ws_size < WS_NEED) return;   // distinctive failure: output stays poisoned

  u16*   xb    = (u16*)(ws + OFF_XB);
  u16*   w1t   = (u16*)(ws + OFF_W1T);
  u16*   w3t   = (u16*)(ws + OFF_W3T);
  u16*   w2t   = (u16*)(ws + OFF_W2T);
  u16*   sw1t  = (u16*)(ws + OFF_SW1T);
  u16*   sw3t  = (u16*)(ws + OFF_SW3T);
  u16*   sw2t  = (u16*)(ws + OFF_SW2T);
  u16*   hbuf  = (u16*)(ws + OFF_H);
  int*   ridx  = (int*)(ws + OFF_RIDX);
  float* rwt   = (float*)(ws + OFF_RW);
  int*   offs  = (int*)(ws + OFF_OFFS);
  int*   ptok  = (int*)(ws + OFF_PTOK);
  float* pw    = (float*)(ws + OFF_PW);

  hipMemsetAsync(y, 0, (size_t)out_size * 4, stream);
  gate_kernel<<<NTOK, 256, 0, stream>>>(x, gw, bias, xb, ridx, rwt);
  transpose_cs_kernel<<<dim3(H_ / 32, C_ / 32, 18), dim3(32, 8), 0, stream>>>(
      w1, w3, sw1, sw3, w1t, w3t, sw1t, sw3t);
  transpose_sc_kernel<<<dim3(C_ / 32, H_ / 32, 9), dim3(32, 8), 0, stream>>>(
      w2, sw2, w2t, sw2t);
  route_scan_kernel<<<1, 256, 0, stream>>>(ridx, rwt, offs, ptok, pw);

  // GEMM1: routed (bx<136) + shared (bx>=136) in one dispatch
  gemm1_m<<<dim3(ROUTED_XB + SHARED_XB, 22), 256, 0, stream>>>(
      xb, w1t, w3t, sw1t, sw3t, hbuf, offs, ptok);
  // GEMM2: one all-atomic dispatch over routed + shared rows (y pre-zeroed)
  gemm2_m<<<dim3(ROUTED_XB + SHARED_XB, 8), 256, 0, stream>>>(
      hbuf, w2t, sw2t, y, offs, ptok, pw);
}